// Round 8
// baseline (149.618 us; speedup 1.0000x reference)
//
#include <hip/hip_runtime.h>

typedef __attribute__((ext_vector_type(8))) short bf8v;   // 8 bf16 (4 VGPRs)
typedef __attribute__((ext_vector_type(4))) float f4v;    // MFMA acc
typedef unsigned short u16;
typedef unsigned int   u32;
#define AS1 __attribute__((address_space(1)))
#define AS3 __attribute__((address_space(3)))

__device__ inline u16 f2b(float f){
  u32 u = __builtin_bit_cast(u32, f);
  u += 0x7fffu + ((u >> 16) & 1u);     // RNE
  return (u16)(u >> 16);
}

// ---------------- merged f32 -> bf16 conversion (x, Wq, Wk, Wv, Wo) ----------------
__global__ __launch_bounds__(256) void conv_all(const float* __restrict__ x,  const float* __restrict__ wq,
                                                const float* __restrict__ wk, const float* __restrict__ wv,
                                                const float* __restrict__ wo,
                                                u16* xb, u16* wqb, u16* wkb, u16* wvb, u16* wob){
  int i = blockIdx.x * 256 + threadIdx.x;
  const float* src; u16* dst; int off;
  if      (i <  524288){ src = x;  dst = xb;  off = i; }
  else if (i < 1048576){ src = wq; dst = wqb; off = i -  524288; }
  else if (i < 1572864){ src = wk; dst = wkb; off = i - 1048576; }
  else if (i < 1835008){ src = wv; dst = wvb; off = i - 1572864; }
  else                 { src = wo; dst = wob; off = i - 1835008; }
  float4 v = ((const float4*)src)[off];
  uint2 r;
  r.x = (u32)f2b(v.x) | ((u32)f2b(v.y) << 16);
  r.y = (u32)f2b(v.z) | ((u32)f2b(v.w) << 16);
  ((uint2*)dst)[off] = r;
}

// ---------------- bt-GEMM core: 128 x (NFR*32) tile, BK=32, 5 buffers, depth-3 counted vmcnt ----
// Main-loop stage is UNCONDITIONAL (waitcnt-scoreboard friendly); drain epilogue 2L->1L->0.
// gload_lds w16 linear dest + inverse-swizzled source (seg ^ (row>>1)&3) + swizzled read.
// A region per buffer = 4096 elems (128x32); B region = NFR*1024 elems ((NFR*32)x32).
template<int NFR>   // 4 -> BN=128, 2 -> BN=64
__device__ __forceinline__ void gemm_core(const u16* __restrict__ A, const u16* __restrict__ B,
                                          int K, int m0, int n0, u16* lds, f4v (&acc)[4][NFR]){
  const int tid = threadIdx.x;
  const int l = tid & 63, w = tid >> 6;
  const int wrow = (w >> 1) * 64, wcol = (w & 1) * (NFR * 16);
  constexpr int SB = 4096 + NFR * 1024;      // buffer stride in elems (8192 / 6144)
  #pragma unroll
  for (int a = 0; a < 4; a++)
    #pragma unroll
    for (int b = 0; b < NFR; b++) acc[a][b] = (f4v)0.0f;

  const int c0 = tid, c1 = tid + 256;
  const int r0 = c0 >> 2, s0 = ((c0 & 3) ^ ((r0 >> 1) & 3)) * 8;
  const int r1 = c1 >> 2, s1 = ((c1 & 3) ^ ((r1 >> 1) & 3)) * 8;

  const u16* Ar0 = A + (size_t)(m0 + r0) * K + s0;
  const u16* Ar1 = A + (size_t)(m0 + r1) * K + s1;
  const u16* Br0 = B + (size_t)(n0 + r0) * K + s0;
  const u16* Br1 = B + (size_t)(n0 + r1) * K + s1;   // unused when NFR==2

  auto stage = [&](int tile, int bi){
    int k0 = tile << 5;
    u16* buf = lds + bi * SB;
    __builtin_amdgcn_global_load_lds((const AS1 void*)(Ar0 + k0), (AS3 void*)(buf + w * 512),        16, 0, 0);
    __builtin_amdgcn_global_load_lds((const AS1 void*)(Ar1 + k0), (AS3 void*)(buf + 2048 + w * 512), 16, 0, 0);
    __builtin_amdgcn_global_load_lds((const AS1 void*)(Br0 + k0), (AS3 void*)(buf + 4096 + w * 512), 16, 0, 0);
    if constexpr (NFR == 4)
      __builtin_amdgcn_global_load_lds((const AS1 void*)(Br1 + k0), (AS3 void*)(buf + 6144 + w * 512), 16, 0, 0);
  };

  const int kb = l >> 4;
  auto compute = [&](int bi){
    const u16* At = lds + bi * SB;
    const u16* Bt = At + 4096;
    bf8v af[4], bfr[NFR];
    #pragma unroll
    for (int mr = 0; mr < 4; mr++){
      int row = wrow + mr * 16 + (l & 15);
      af[mr] = *(const bf8v*)(At + row * 32 + ((kb ^ ((row >> 1) & 3)) * 8));
    }
    #pragma unroll
    for (int nc = 0; nc < NFR; nc++){
      int row = wcol + nc * 16 + (l & 15);
      bfr[nc] = *(const bf8v*)(Bt + row * 32 + ((kb ^ ((row >> 1) & 3)) * 8));
    }
    __builtin_amdgcn_s_setprio(1);
    #pragma unroll
    for (int mr = 0; mr < 4; mr++)
      #pragma unroll
      for (int nc = 0; nc < NFR; nc++)
        acc[mr][nc] = __builtin_amdgcn_mfma_f32_16x16x32_bf16(af[mr], bfr[nc], acc[mr][nc], 0, 0, 0);
    __builtin_amdgcn_s_setprio(0);
  };

  const int nst = K >> 5;            // assumes nst >= 4
  stage(0, 0); stage(1, 1); stage(2, 2);
  int cbuf = 0, sbuf = 3;
  for (int i = 0; i < nst - 3; ++i){               // steady state: UNCONDITIONAL stage
    stage(i + 3, sbuf);
    sbuf = (sbuf == 4) ? 0 : sbuf + 1;
    if constexpr (NFR == 4) asm volatile("s_waitcnt vmcnt(12)" ::: "memory");
    else                    asm volatile("s_waitcnt vmcnt(9)"  ::: "memory");
    __builtin_amdgcn_s_barrier();
    compute(cbuf);
    cbuf = (cbuf == 4) ? 0 : cbuf + 1;
  }
  // drain epilogue: 2L -> 1L -> 0
  if constexpr (NFR == 4) asm volatile("s_waitcnt vmcnt(8)" ::: "memory");
  else                    asm volatile("s_waitcnt vmcnt(6)" ::: "memory");
  __builtin_amdgcn_s_barrier();
  compute(cbuf); cbuf = (cbuf == 4) ? 0 : cbuf + 1;
  if constexpr (NFR == 4) asm volatile("s_waitcnt vmcnt(4)" ::: "memory");
  else                    asm volatile("s_waitcnt vmcnt(3)" ::: "memory");
  __builtin_amdgcn_s_barrier();
  compute(cbuf); cbuf = (cbuf == 4) ? 0 : cbuf + 1;
  asm volatile("s_waitcnt vmcnt(0)" ::: "memory");
  __builtin_amdgcn_s_barrier();
  compute(cbuf);
}

// Q/K -> bf16 scores; V -> transposed bf16 [h][d][t] directly
__global__ __launch_bounds__(256) void qkv_gemm(const u16* __restrict__ xb,
                                                const u16* __restrict__ wqb, const u16* __restrict__ wkb,
                                                const u16* __restrict__ wvb,
                                                u16* qf, u16* kf, u16* vtb){
  __shared__ u16 lds[40960];   // 80 KB: 5 x 8192
  int b = (blockIdx.x & 7) * 80 + (blockIdx.x >> 3);   // bijective XCD swizzle (640 = 8*80)
  const u16* Bp; int which;    // 0=Q 1=K 2=V
  if (b < 256)      { Bp = wqb; which = 0; }
  else if (b < 512) { Bp = wkb; which = 1; b -= 256; }
  else              { Bp = wvb; which = 2; b -= 512; }
  int sh = (which == 2) ? 3 : 4;
  int m0 = (b >> sh) * 128, n0 = (b & ((1 << sh) - 1)) * 128;

  f4v acc[4][4];
  gemm_core<4>(xb, Bp, 1024, m0, n0, lds, acc);

  const int l = threadIdx.x & 63, w = threadIdx.x >> 6;
  const int wrow = (w >> 1) * 64, wcol = (w & 1) * 64;
  if (which < 2){
    u16* C = which ? kf : qf;
    #pragma unroll
    for (int mr = 0; mr < 4; mr++)
      #pragma unroll
      for (int nc = 0; nc < 4; nc++)
        #pragma unroll
        for (int rr = 0; rr < 4; rr++){
          int row = m0 + wrow + mr * 16 + (l >> 4) * 4 + rr;
          int col = n0 + wcol + nc * 16 + (l & 15);
          C[(size_t)row * 2048 + col] = f2b(acc[mr][nc][rr]);
        }
  } else {
    #pragma unroll
    for (int mr = 0; mr < 4; mr++)
      #pragma unroll
      for (int nc = 0; nc < 4; nc++){
        int gcol = n0 + wcol + nc * 16 + (l & 15);
        int t0 = m0 + wrow + mr * 16 + (l >> 4) * 4;
        uint2 pk;
        pk.x = (u32)f2b(acc[mr][nc][0]) | ((u32)f2b(acc[mr][nc][1]) << 16);
        pk.y = (u32)f2b(acc[mr][nc][2]) | ((u32)f2b(acc[mr][nc][3]) << 16);
        *(uint2*)(vtb + (size_t)gcol * 2048 + t0) = pk;   // gcol = h*64+d
      }
  }
}

// out[2048,1024] = yb[2048,1024] @ wob[1024,1024]^T — 128x64 tiles -> 256 blocks (1/CU)
__global__ __launch_bounds__(256) void o_gemm(const u16* __restrict__ yb, const u16* __restrict__ wob,
                                              float* out){
  __shared__ u16 lds[30720];   // 60 KB: 5 x 6144
  int b = (blockIdx.x & 7) * 32 + (blockIdx.x >> 3);   // 256 = 8*32
  int m0 = (b >> 4) * 128, n0 = (b & 15) * 64;
  f4v acc[4][2];
  gemm_core<2>(yb, wob, 1024, m0, n0, lds, acc);
  const int l = threadIdx.x & 63, w = threadIdx.x >> 6;
  const int wrow = (w >> 1) * 64, wcol = (w & 1) * 32;
  #pragma unroll
  for (int mr = 0; mr < 4; mr++)
    #pragma unroll
    for (int nc = 0; nc < 2; nc++)
      #pragma unroll
      for (int rr = 0; rr < 4; rr++){
        int row = m0 + wrow + mr * 16 + (l >> 4) * 4 + rr;
        int col = n0 + wcol + nc * 16 + (l & 15);
        out[(size_t)row * 1024 + col] = acc[mr][nc][rr];
      }
}

// ---------------- merged ReLU + top-32-of-128 (bf16 inputs, 15-bit radix) ----------------
__global__ __launch_bounds__(256) void topk2(const u16* __restrict__ qf, const u16* __restrict__ kf,
                                             u16* __restrict__ qsb, u16* __restrict__ ksb){
  int w = threadIdx.x >> 6, l = threadIdx.x & 63;
  int b = blockIdx.x;
  const u16* src; u16* dst;
  if (b < 8192){ src = qf; dst = qsb; } else { src = kf; dst = ksb; b -= 8192; }
  int row = b * 4 + w;
  int t = row >> 4, h = row & 15;
  u32 pair = ((const u32*)(src + (size_t)t * 2048 + h * 128))[l];
  u32 u0 = pair & 0xFFFFu, u1 = pair >> 16;
  if (u0 & 0x8000u) u0 = 0;   // ReLU
  if (u1 & 0x8000u) u1 = 0;
  u32 pre = 0;
  for (int bb = 14; bb >= 0; --bb){
    u32 cand = pre | (1u << bb);
    int c = __builtin_popcountll(__ballot(u0 >= cand)) + __builtin_popcountll(__ballot(u1 >= cand));
    if (c >= 32) pre = cand;
  }
  u32 o0 = (u0 >= pre) ? u0 : 0u;
  u32 o1 = (u1 >= pre) ? u1 : 0u;
  ((u32*)(dst + ((size_t)h * 2048 + t) * 128))[l] = o0 | (o1 << 16);
}

// ---------------- chunk-parallel causal p=1 attention (8 waves, dbuf, gload_lds) ----------------
__global__ __launch_bounds__(512) void attn3(const u16* __restrict__ qs, const u16* __restrict__ ks,
                                             const u16* __restrict__ vt, const float* __restrict__ sink,
                                             const float* __restrict__ logbeta, u16* __restrict__ yout,
                                             float* __restrict__ Yp, float* __restrict__ Dp){
  __shared__ u16 Kt[2][8192];
  __shared__ u16 Vt[2][4096];
  __shared__ u16 St[8][16 * 72];
  const int tid = threadIdx.x, l = tid & 63, w = tid >> 6;
  const int b = blockIdx.x;
  const int slot = b >> 3;
  const int h = (b & 7) + 8 * (slot / 40);
  const int u = slot % 40;
  int it, chunk, nch;
  if (u < 4)       { it = u; chunk = 0; nch = 1; }
  else if (u < 12) { it = 4 + ((u - 4) >> 1);  chunk = (u - 4) & 1;  nch = 2; }
  else if (u < 24) { it = 8 + (u - 12) / 3;    chunk = (u - 12) % 3; nch = 3; }
  else             { it = 12 + ((u - 24) >> 2); chunk = (u - 24) & 3; nch = 4; }
  const int tiles = 2 * it + 2;
  const int jt0 = (tiles * chunk) / nch;        // balanced partition
  const int jt1 = (tiles * (chunk + 1)) / nch;
  const int qrow0 = it * 128 + w * 16;
  const float beta = expf(logbeta[0]);

  bf8v qfr[4];
  {
    int trow = qrow0 + (l & 15);
    const u16* qrow = qs + ((size_t)h * 2048 + trow) * 128 + (l >> 4) * 8;
    #pragma unroll
    for (int kk = 0; kk < 4; kk++) qfr[kk] = *(const bf8v*)(qrow + kk * 32);
  }

  f4v accY[4];
  #pragma unroll
  for (int c = 0; c < 4; c++) accY[c] = (f4v)0.0f;
  float dsum[4] = {0.f, 0.f, 0.f, 0.f};

  const u16* kroot = ks + (size_t)h * 2048 * 128;
  const u16* vroot = vt + (size_t)h * 64 * 2048;

  auto stage = [&](int jt, int buf){
    const u16* kbase = kroot + (size_t)jt * 64 * 128;
    #pragma unroll
    for (int i = 0; i < 2; i++){
      int g = i * 512 + tid;
      int r = g >> 4, c = g & 15;
      __builtin_amdgcn_global_load_lds((const AS1 void*)(kbase + r * 128 + (c ^ (r & 7)) * 8),
                                       (AS3 void*)(&Kt[buf][(i * 512 + w * 64) * 8]), 16, 0, 0);
    }
    {
      int d = tid >> 3, c = tid & 7;
      __builtin_amdgcn_global_load_lds((const AS1 void*)(vroot + (size_t)d * 2048 + jt * 64 + (c ^ (d & 7)) * 8),
                                       (AS3 void*)(&Vt[buf][w * 512]), 16, 0, 0);
    }
  };

  stage(jt0, 0);
  __syncthreads();
  int buf = 0;
  for (int jt = jt0; jt < jt1; ++jt){
    if (jt + 1 < jt1) stage(jt + 1, buf ^ 1);

    if (jt * 64 <= qrow0 + 15){
      f4v accS[4];
      #pragma unroll
      for (int c = 0; c < 4; c++) accS[c] = (f4v)0.0f;
      __builtin_amdgcn_s_setprio(1);
      #pragma unroll
      for (int c = 0; c < 4; c++){
        int r = c * 16 + (l & 15);
        #pragma unroll
        for (int kk = 0; kk < 4; kk++){
          int ch = kk * 4 + (l >> 4);
          bf8v kfr = *(const bf8v*)(&Kt[buf][r * 128 + ((ch ^ (r & 7)) * 8)]);
          accS[c] = __builtin_amdgcn_mfma_f32_16x16x32_bf16(qfr[kk], kfr, accS[c], 0, 0, 0);
        }
      }
      __builtin_amdgcn_s_setprio(0);
      if (jt * 64 + 63 > qrow0){
        #pragma unroll
        for (int c = 0; c < 4; c++)
          #pragma unroll
          for (int rr = 0; rr < 4; rr++){
            int i = qrow0 + (l >> 4) * 4 + rr;
            int j = jt * 64 + c * 16 + (l & 15);
            if (j > i) accS[c][rr] = 0.f;
          }
      }
      #pragma unroll
      for (int c = 0; c < 4; c++)
        #pragma unroll
        for (int rr = 0; rr < 4; rr++){
          dsum[rr] += accS[c][rr];
          St[w][((l >> 4) * 4 + rr) * 72 + c * 16 + (l & 15)] = f2b(accS[c][rr]);
        }
      __builtin_amdgcn_s_setprio(1);
      #pragma unroll
      for (int k2 = 0; k2 < 2; k2++){
        bf8v afr = *(const bf8v*)(&St[w][(l & 15) * 72 + k2 * 32 + (l >> 4) * 8]);
        #pragma unroll
        for (int c = 0; c < 4; c++){
          int d = c * 16 + (l & 15);
          int ch = k2 * 4 + (l >> 4);
          bf8v vfr = *(const bf8v*)(&Vt[buf][d * 64 + ((ch ^ (d & 7)) * 8)]);
          accY[c] = __builtin_amdgcn_mfma_f32_16x16x32_bf16(afr, vfr, accY[c], 0, 0, 0);
        }
      }
      __builtin_amdgcn_s_setprio(0);
    }
    __syncthreads();
    buf ^= 1;
  }

  #pragma unroll
  for (int rr = 0; rr < 4; rr++){
    float s = dsum[rr];
    s += __shfl_xor(s, 1, 64);
    s += __shfl_xor(s, 2, 64);
    s += __shfl_xor(s, 4, 64);
    s += __shfl_xor(s, 8, 64);
    dsum[rr] = s;
  }

  if (nch == 1){
    #pragma unroll
    for (int c = 0; c < 4; c++){
      float sv = sink[h * 64 + c * 16 + (l & 15)];
      #pragma unroll
      for (int rr = 0; rr < 4; rr++){
        float den = dsum[rr] + beta;
        float inv = 1.0f / fmaxf(den, 1e-12f);
        float y = (accY[c][rr] + beta * sv) * inv;
        int row = qrow0 + (l >> 4) * 4 + rr;
        yout[(size_t)row * 1024 + h * 64 + c * 16 + (l & 15)] = f2b(y);
      }
    }
  } else {
    float* yp = Yp + ((size_t)h * 40 + u) * 8192;
    #pragma unroll
    for (int c = 0; c < 4; c++)
      #pragma unroll
      for (int rr = 0; rr < 4; rr++){
        int rowib = w * 16 + (l >> 4) * 4 + rr;
        yp[rowib * 64 + c * 16 + (l & 15)] = accY[c][rr];
      }
    if ((l & 15) == 0){
      #pragma unroll
      for (int rr = 0; rr < 4; rr++)
        Dp[((size_t)h * 40 + u) * 128 + w * 16 + (l >> 4) * 4 + rr] = dsum[rr];
    }
  }
}

// combine partials for it 4..15 (grid 16 x 12)
__global__ __launch_bounds__(256) void attn_reduce(const float* __restrict__ Yp, const float* __restrict__ Dp,
                                                   const float* __restrict__ sink, const float* __restrict__ logbeta,
                                                   u16* __restrict__ yout){
  int blk = blockIdx.x;
  int h = blk / 12, it = 4 + blk % 12;
  int nch = it / 4 + 1;
  int u0 = (it < 8) ? 4 + (it - 4) * 2 : (it < 12) ? 12 + (it - 8) * 3 : 24 + (it - 12) * 4;
  float beta = expf(logbeta[0]);
  __shared__ float inv_s[128];
  int t = threadIdx.x;
  if (t < 128){
    float s = 0.f;
    for (int c = 0; c < nch; c++) s += Dp[((size_t)h * 40 + u0 + c) * 128 + t];
    inv_s[t] = 1.0f / fmaxf(s + beta, 1e-12f);
  }
  __syncthreads();
  const float* base = Yp + ((size_t)h * 40 + u0) * 8192;
  #pragma unroll
  for (int e = 0; e < 32; e++){
    int idx = e * 256 + t;
    float acc = 0.f;
    for (int c = 0; c < nch; c++) acc += base[c * 8192 + idx];
    int row = idx >> 6, col = idx & 63;
    float y = (acc + beta * sink[h * 64 + col]) * inv_s[row];
    yout[(size_t)(it * 128 + row) * 1024 + h * 64 + col] = f2b(y);
  }
}

extern "C" void kernel_launch(void* const* d_in, const int* in_sizes, int n_in,
                              void* d_out, int out_size, void* d_ws, size_t ws_size,
                              hipStream_t stream){
  const float* x    = (const float*)d_in[0];
  const float* Wq   = (const float*)d_in[1];
  const float* Wk   = (const float*)d_in[2];
  const float* Wv   = (const float*)d_in[3];
  const float* Wo   = (const float*)d_in[4];
  const float* sink = (const float*)d_in[5];
  const float* logb = (const float*)d_in[6];

  char* ws = (char*)d_ws;
  u16*   xb  = (u16*)(ws + 0);            // 4 MB
  u16*   wqb = (u16*)(ws + 4194304);      // 4 MB
  u16*   wkb = (u16*)(ws + 8388608);      // 4 MB
  u16*   wvb = (u16*)(ws + 12582912);     // 2 MB
  u16*   wob = (u16*)(ws + 14680064);     // 2 MB
  u16*   qf  = (u16*)(ws + 16777216);     // 8 MB bf16 scores (live: qkv_gemm -> topk2)
  u16*   kf  = (u16*)(ws + 33554432);     // 8 MB bf16 scores (live: qkv_gemm -> topk2)
  u16*   qsb = (u16*)(ws + 50331648);     // 8 MB  [16][2048][128]
  u16*   ksb = (u16*)(ws + 58720256);     // 8 MB
  u16*   vtb = (u16*)(ws + 67108864);     // 4 MB  V^T [16][64][2048]
  u16*   yb  = (u16*)(ws + 71303168);     // 4 MB  [2048][1024]
  float* Yp  = (float*)(ws + 16777216);   // 21 MB partials (overlays qf/kf AFTER topk2)
  float* Dp  = (float*)(ws + 37748736);   // 320 KB (dead kf region, after topk2)

  conv_all<<<8192, 256, 0, stream>>>(x, Wq, Wk, Wv, Wo, xb, wqb, wkb, wvb, wob);
  qkv_gemm<<<640, 256, 0, stream>>>(xb, wqb, wkb, wvb, qf, kf, vtb);
  topk2<<<16384, 256, 0, stream>>>(qf, kf, qsb, ksb);
  attn3<<<640, 512, 0, stream>>>(qsb, ksb, vtb, sink, logb, yb, Yp, Dp);
  attn_reduce<<<192, 256, 0, stream>>>(Yp, Dp, sink, logb, yb);
  o_gemm<<<256, 256, 0, stream>>>(yb, wob, (float*)d_out);
}

// Round 9
// 149.585 us; speedup vs baseline: 1.0002x; 1.0002x over previous
//
#include <hip/hip_runtime.h>

typedef __attribute__((ext_vector_type(8))) short bf8v;   // 8 bf16 (4 VGPRs)
typedef __attribute__((ext_vector_type(4))) float f4v;    // MFMA acc
typedef unsigned short u16;
typedef unsigned int   u32;
#define AS1 __attribute__((address_space(1)))
#define AS3 __attribute__((address_space(3)))

__device__ inline u16 f2b(float f){
  u32 u = __builtin_bit_cast(u32, f);
  u += 0x7fffu + ((u >> 16) & 1u);     // RNE
  return (u16)(u >> 16);
}

// ---------------- merged f32 -> bf16 conversion (x, Wq, Wk, Wv, Wo) ----------------
__global__ __launch_bounds__(256) void conv_all(const float* __restrict__ x,  const float* __restrict__ wq,
                                                const float* __restrict__ wk, const float* __restrict__ wv,
                                                const float* __restrict__ wo,
                                                u16* xb, u16* wqb, u16* wkb, u16* wvb, u16* wob){
  int i = blockIdx.x * 256 + threadIdx.x;
  const float* src; u16* dst; int off;
  if      (i <  524288){ src = x;  dst = xb;  off = i; }
  else if (i < 1048576){ src = wq; dst = wqb; off = i -  524288; }
  else if (i < 1572864){ src = wk; dst = wkb; off = i - 1048576; }
  else if (i < 1835008){ src = wv; dst = wvb; off = i - 1572864; }
  else                 { src = wo; dst = wob; off = i - 1835008; }
  float4 v = ((const float4*)src)[off];
  uint2 r;
  r.x = (u32)f2b(v.x) | ((u32)f2b(v.y) << 16);
  r.y = (u32)f2b(v.z) | ((u32)f2b(v.w) << 16);
  ((uint2*)dst)[off] = r;
}

// ---------------- bt-GEMM core (R5 structure): A 128xK tile, B (NFR*32)xK tile, BK=64 ----------
// 2 LDS buffers, prefetch(k+1) BEFORE compute(k), one __syncthreads per step.
// gload_lds w16 linear dest + inverse-swizzled source + swizzled read (k-seg ^ row&7).
template<int NFR>   // 4 -> BN=128, 2 -> BN=64
__device__ __forceinline__ void gemm_core(const u16* __restrict__ A, const u16* __restrict__ B,
                                          int K, int m0, int n0, u16* lds, f4v (&acc)[4][NFR]){
  const int tid = threadIdx.x;
  const int l = tid & 63, w = tid >> 6;
  const int wrow = (w >> 1) * 64, wcol = (w & 1) * (NFR * 16);
  constexpr int SB = 8192 + NFR * 2048;      // buffer stride in elems: A 8192 + B NFR*2048
  #pragma unroll
  for (int a = 0; a < 4; a++)
    #pragma unroll
    for (int b = 0; b < NFR; b++) acc[a][b] = (f4v)0.0f;

  const int crow = l >> 3;                   // 0..7
  const int ksrc = ((l & 7) ^ crow) * 8;     // inverse-swizzled k-segment (elems)

  auto stage = [&](int k0, int buf){
    const u16* Ab = A + (size_t)m0 * K + k0;
    const u16* Bb = B + (size_t)n0 * K + k0;
    u16* At = lds + buf * SB;
    u16* Bt = At + 8192;
    #pragma unroll
    for (int c = 0; c < 4; c++){
      int chunk = w * 4 + c;
      int row = chunk * 8 + crow;
      __builtin_amdgcn_global_load_lds((const AS1 void*)(Ab + (size_t)row * K + ksrc),
                                       (AS3 void*)(At + chunk * 512), 16, 0, 0);
    }
    if constexpr (NFR == 4){
      #pragma unroll
      for (int c = 0; c < 4; c++){
        int chunk = w * 4 + c;
        int row = chunk * 8 + crow;
        __builtin_amdgcn_global_load_lds((const AS1 void*)(Bb + (size_t)row * K + ksrc),
                                         (AS3 void*)(Bt + chunk * 512), 16, 0, 0);
      }
    } else {
      #pragma unroll
      for (int c = 0; c < 2; c++){
        int chunk = w * 2 + c;
        int row = chunk * 8 + crow;
        __builtin_amdgcn_global_load_lds((const AS1 void*)(Bb + (size_t)row * K + ksrc),
                                         (AS3 void*)(Bt + chunk * 512), 16, 0, 0);
      }
    }
  };

  stage(0, 0);
  __syncthreads();
  int buf = 0;
  for (int k0 = 0; k0 < K; k0 += 64){
    if (k0 + 64 < K) stage(k0 + 64, buf ^ 1);   // prefetch overlaps this step's compute
    const u16* At = lds + buf * SB;
    const u16* Bt = At + 8192;
    #pragma unroll
    for (int kk = 0; kk < 2; kk++){
      bf8v af[4], bfr[NFR];
      #pragma unroll
      for (int mr = 0; mr < 4; mr++){
        int row = wrow + mr * 16 + (l & 15);
        af[mr] = *(const bf8v*)(At + row * 64 + (((kk * 32 + (l >> 4) * 8)) ^ ((row & 7) * 8)));
      }
      #pragma unroll
      for (int nc = 0; nc < NFR; nc++){
        int row = wcol + nc * 16 + (l & 15);
        bfr[nc] = *(const bf8v*)(Bt + row * 64 + (((kk * 32 + (l >> 4) * 8)) ^ ((row & 7) * 8)));
      }
      #pragma unroll
      for (int mr = 0; mr < 4; mr++)
        #pragma unroll
        for (int nc = 0; nc < NFR; nc++)
          acc[mr][nc] = __builtin_amdgcn_mfma_f32_16x16x32_bf16(af[mr], bfr[nc], acc[mr][nc], 0, 0, 0);
    }
    __syncthreads();   // drains prefetch + read/write hazard
    buf ^= 1;
  }
}

// Q/K -> fused ReLU+top-32 -> qsb/ksb [h][t][128]; V -> transposed bf16 vtb[h][d][t]
__global__ __launch_bounds__(256) void qkv_gemm(const u16* __restrict__ xb,
                                                const u16* __restrict__ wqb, const u16* __restrict__ wkb,
                                                const u16* __restrict__ wvb,
                                                u16* qsb, u16* ksb, u16* vtb){
  __shared__ u16 lds[32768];   // 64 KB: 2 x (A 16KB + B 16KB); reused as Sc[128][132] in epilogue
  int b = (blockIdx.x & 7) * 80 + (blockIdx.x >> 3);   // bijective XCD swizzle (640 = 8*80)
  const u16* Bp; int which;    // 0=Q 1=K 2=V
  if (b < 256)      { Bp = wqb; which = 0; }
  else if (b < 512) { Bp = wkb; which = 1; b -= 256; }
  else              { Bp = wvb; which = 2; b -= 512; }
  int sh = (which == 2) ? 3 : 4;
  int m0 = (b >> sh) * 128, n0 = (b & ((1 << sh) - 1)) * 128;

  f4v acc[4][4];
  gemm_core<4>(xb, Bp, 1024, m0, n0, lds, acc);

  const int l = threadIdx.x & 63, w = threadIdx.x >> 6;
  const int wrow = (w >> 1) * 64, wcol = (w & 1) * 64;
  if (which < 2){
    // ---- fused ReLU + top-32-of-128 epilogue (n-tile == one head's full lift row) ----
    u16* Sc = lds;               // [128][132] bf16, stride 132 -> 2-way (free) access
    #pragma unroll
    for (int mr = 0; mr < 4; mr++)
      #pragma unroll
      for (int nc = 0; nc < 4; nc++)
        #pragma unroll
        for (int rr = 0; rr < 4; rr++){
          int row = wrow + mr * 16 + (l >> 4) * 4 + rr;
          int col = wcol + nc * 16 + (l & 15);
          float v = acc[mr][nc][rr];
          Sc[row * 132 + col] = (v > 0.f) ? f2b(v) : (u16)0;
        }
    __syncthreads();
    u16* dst = which ? ksb : qsb;
    const int h = n0 >> 7;
    for (int r2 = 0; r2 < 32; ++r2){
      int r = w * 32 + r2;
      u32 pair = *(const u32*)(Sc + r * 132 + l * 2);
      u32 u0 = pair & 0xFFFFu, u1 = pair >> 16;
      u32 pre = 0;
      for (int bb = 14; bb >= 0; --bb){
        u32 cand = pre | (1u << bb);
        int c = __builtin_popcountll(__ballot(u0 >= cand)) + __builtin_popcountll(__ballot(u1 >= cand));
        if (c >= 32) pre = cand;
      }
      u32 o0 = (u0 >= pre) ? u0 : 0u;
      u32 o1 = (u1 >= pre) ? u1 : 0u;
      ((u32*)(dst + ((size_t)h * 2048 + m0 + r) * 128))[l] = o0 | (o1 << 16);
    }
  } else {
    // transposed store: vtb[h][d][t], 4 consecutive t packed per uint2
    #pragma unroll
    for (int mr = 0; mr < 4; mr++)
      #pragma unroll
      for (int nc = 0; nc < 4; nc++){
        int gcol = n0 + wcol + nc * 16 + (l & 15);
        int t0 = m0 + wrow + mr * 16 + (l >> 4) * 4;
        uint2 pk;
        pk.x = (u32)f2b(acc[mr][nc][0]) | ((u32)f2b(acc[mr][nc][1]) << 16);
        pk.y = (u32)f2b(acc[mr][nc][2]) | ((u32)f2b(acc[mr][nc][3]) << 16);
        *(uint2*)(vtb + (size_t)gcol * 2048 + t0) = pk;   // gcol = h*64+d
      }
  }
}

// out[2048,1024] = yb @ wob^T — 128x64 tiles -> 256 blocks (1/CU)
__global__ __launch_bounds__(256) void o_gemm(const u16* __restrict__ yb, const u16* __restrict__ wob,
                                              float* out){
  __shared__ u16 lds[24576];   // 48 KB: 2 x (A 16KB + B 8KB)
  int b = (blockIdx.x & 7) * 32 + (blockIdx.x >> 3);   // 256 = 8*32
  int m0 = (b >> 4) * 128, n0 = (b & 15) * 64;
  f4v acc[4][2];
  gemm_core<2>(yb, wob, 1024, m0, n0, lds, acc);
  const int l = threadIdx.x & 63, w = threadIdx.x >> 6;
  const int wrow = (w >> 1) * 64, wcol = (w & 1) * 32;
  #pragma unroll
  for (int mr = 0; mr < 4; mr++)
    #pragma unroll
    for (int nc = 0; nc < 2; nc++)
      #pragma unroll
      for (int rr = 0; rr < 4; rr++){
        int row = m0 + wrow + mr * 16 + (l >> 4) * 4 + rr;
        int col = n0 + wcol + nc * 16 + (l & 15);
        out[(size_t)row * 1024 + col] = acc[mr][nc][rr];
      }
}

// ---------------- chunk-parallel causal p=1 attention (8 waves, dbuf, gload_lds) ----------------
__global__ __launch_bounds__(512) void attn3(const u16* __restrict__ qs, const u16* __restrict__ ks,
                                             const u16* __restrict__ vt, const float* __restrict__ sink,
                                             const float* __restrict__ logbeta, u16* __restrict__ yout,
                                             float* __restrict__ Yp, float* __restrict__ Dp){
  __shared__ u16 Kt[2][8192];
  __shared__ u16 Vt[2][4096];
  __shared__ u16 St[8][16 * 72];
  const int tid = threadIdx.x, l = tid & 63, w = tid >> 6;
  const int b = blockIdx.x;
  const int slot = b >> 3;
  const int h = (b & 7) + 8 * (slot / 40);
  const int u = slot % 40;
  int it, chunk, nch;
  if (u < 4)       { it = u; chunk = 0; nch = 1; }
  else if (u < 12) { it = 4 + ((u - 4) >> 1);  chunk = (u - 4) & 1;  nch = 2; }
  else if (u < 24) { it = 8 + (u - 12) / 3;    chunk = (u - 12) % 3; nch = 3; }
  else             { it = 12 + ((u - 24) >> 2); chunk = (u - 24) & 3; nch = 4; }
  const int tiles = 2 * it + 2;
  const int jt0 = (tiles * chunk) / nch;        // balanced partition
  const int jt1 = (tiles * (chunk + 1)) / nch;
  const int qrow0 = it * 128 + w * 16;
  const float beta = expf(logbeta[0]);

  bf8v qfr[4];
  {
    int trow = qrow0 + (l & 15);
    const u16* qrow = qs + ((size_t)h * 2048 + trow) * 128 + (l >> 4) * 8;
    #pragma unroll
    for (int kk = 0; kk < 4; kk++) qfr[kk] = *(const bf8v*)(qrow + kk * 32);
  }

  f4v accY[4];
  #pragma unroll
  for (int c = 0; c < 4; c++) accY[c] = (f4v)0.0f;
  float dsum[4] = {0.f, 0.f, 0.f, 0.f};

  const u16* kroot = ks + (size_t)h * 2048 * 128;
  const u16* vroot = vt + (size_t)h * 64 * 2048;

  auto stage = [&](int jt, int buf){
    const u16* kbase = kroot + (size_t)jt * 64 * 128;
    #pragma unroll
    for (int i = 0; i < 2; i++){
      int g = i * 512 + tid;
      int r = g >> 4, c = g & 15;
      __builtin_amdgcn_global_load_lds((const AS1 void*)(kbase + r * 128 + (c ^ (r & 7)) * 8),
                                       (AS3 void*)(&Kt[buf][(i * 512 + w * 64) * 8]), 16, 0, 0);
    }
    {
      int d = tid >> 3, c = tid & 7;
      __builtin_amdgcn_global_load_lds((const AS1 void*)(vroot + (size_t)d * 2048 + jt * 64 + (c ^ (d & 7)) * 8),
                                       (AS3 void*)(&Vt[buf][w * 512]), 16, 0, 0);
    }
  };

  stage(jt0, 0);
  __syncthreads();
  int buf = 0;
  for (int jt = jt0; jt < jt1; ++jt){
    if (jt + 1 < jt1) stage(jt + 1, buf ^ 1);

    if (jt * 64 <= qrow0 + 15){
      f4v accS[4];
      #pragma unroll
      for (int c = 0; c < 4; c++) accS[c] = (f4v)0.0f;
      __builtin_amdgcn_s_setprio(1);
      #pragma unroll
      for (int c = 0; c < 4; c++){
        int r = c * 16 + (l & 15);
        #pragma unroll
        for (int kk = 0; kk < 4; kk++){
          int ch = kk * 4 + (l >> 4);
          bf8v kfr = *(const bf8v*)(&Kt[buf][r * 128 + ((ch ^ (r & 7)) * 8)]);
          accS[c] = __builtin_amdgcn_mfma_f32_16x16x32_bf16(qfr[kk], kfr, accS[c], 0, 0, 0);
        }
      }
      __builtin_amdgcn_s_setprio(0);
      if (jt * 64 + 63 > qrow0){
        #pragma unroll
        for (int c = 0; c < 4; c++)
          #pragma unroll
          for (int rr = 0; rr < 4; rr++){
            int i = qrow0 + (l >> 4) * 4 + rr;
            int j = jt * 64 + c * 16 + (l & 15);
            if (j > i) accS[c][rr] = 0.f;
          }
      }
      #pragma unroll
      for (int c = 0; c < 4; c++)
        #pragma unroll
        for (int rr = 0; rr < 4; rr++){
          dsum[rr] += accS[c][rr];
          St[w][((l >> 4) * 4 + rr) * 72 + c * 16 + (l & 15)] = f2b(accS[c][rr]);
        }
      __builtin_amdgcn_s_setprio(1);
      #pragma unroll
      for (int k2 = 0; k2 < 2; k2++){
        bf8v afr = *(const bf8v*)(&St[w][(l & 15) * 72 + k2 * 32 + (l >> 4) * 8]);
        #pragma unroll
        for (int c = 0; c < 4; c++){
          int d = c * 16 + (l & 15);
          int ch = k2 * 4 + (l >> 4);
          bf8v vfr = *(const bf8v*)(&Vt[buf][d * 64 + ((ch ^ (d & 7)) * 8)]);
          accY[c] = __builtin_amdgcn_mfma_f32_16x16x32_bf16(afr, vfr, accY[c], 0, 0, 0);
        }
      }
      __builtin_amdgcn_s_setprio(0);
    }
    __syncthreads();
    buf ^= 1;
  }

  #pragma unroll
  for (int rr = 0; rr < 4; rr++){
    float s = dsum[rr];
    s += __shfl_xor(s, 1, 64);
    s += __shfl_xor(s, 2, 64);
    s += __shfl_xor(s, 4, 64);
    s += __shfl_xor(s, 8, 64);
    dsum[rr] = s;
  }

  if (nch == 1){
    #pragma unroll
    for (int c = 0; c < 4; c++){
      float sv = sink[h * 64 + c * 16 + (l & 15)];
      #pragma unroll
      for (int rr = 0; rr < 4; rr++){
        float den = dsum[rr] + beta;
        float inv = 1.0f / fmaxf(den, 1e-12f);
        float y = (accY[c][rr] + beta * sv) * inv;
        int row = qrow0 + (l >> 4) * 4 + rr;
        yout[(size_t)row * 1024 + h * 64 + c * 16 + (l & 15)] = f2b(y);
      }
    }
  } else {
    float* yp = Yp + ((size_t)h * 40 + u) * 8192;
    #pragma unroll
    for (int c = 0; c < 4; c++)
      #pragma unroll
      for (int rr = 0; rr < 4; rr++){
        int rowib = w * 16 + (l >> 4) * 4 + rr;
        yp[rowib * 64 + c * 16 + (l & 15)] = accY[c][rr];
      }
    if ((l & 15) == 0){
      #pragma unroll
      for (int rr = 0; rr < 4; rr++)
        Dp[((size_t)h * 40 + u) * 128 + w * 16 + (l >> 4) * 4 + rr] = dsum[rr];
    }
  }
}

// combine partials for it 4..15 (grid 16 x 12)
__global__ __launch_bounds__(256) void attn_reduce(const float* __restrict__ Yp, const float* __restrict__ Dp,
                                                   const float* __restrict__ sink, const float* __restrict__ logbeta,
                                                   u16* __restrict__ yout){
  int blk = blockIdx.x;
  int h = blk / 12, it = 4 + blk % 12;
  int nch = it / 4 + 1;
  int u0 = (it < 8) ? 4 + (it - 4) * 2 : (it < 12) ? 12 + (it - 8) * 3 : 24 + (it - 12) * 4;
  float beta = expf(logbeta[0]);
  __shared__ float inv_s[128];
  int t = threadIdx.x;
  if (t < 128){
    float s = 0.f;
    for (int c = 0; c < nch; c++) s += Dp[((size_t)h * 40 + u0 + c) * 128 + t];
    inv_s[t] = 1.0f / fmaxf(s + beta, 1e-12f);
  }
  __syncthreads();
  const float* base = Yp + ((size_t)h * 40 + u0) * 8192;
  #pragma unroll
  for (int e = 0; e < 32; e++){
    int idx = e * 256 + t;
    float acc = 0.f;
    for (int c = 0; c < nch; c++) acc += base[c * 8192 + idx];
    int row = idx >> 6, col = idx & 63;
    float y = (acc + beta * sink[h * 64 + col]) * inv_s[row];
    yout[(size_t)(it * 128 + row) * 1024 + h * 64 + col] = f2b(y);
  }
}

extern "C" void kernel_launch(void* const* d_in, const int* in_sizes, int n_in,
                              void* d_out, int out_size, void* d_ws, size_t ws_size,
                              hipStream_t stream){
  const float* x    = (const float*)d_in[0];
  const float* Wq   = (const float*)d_in[1];
  const float* Wk   = (const float*)d_in[2];
  const float* Wv   = (const float*)d_in[3];
  const float* Wo   = (const float*)d_in[4];
  const float* sink = (const float*)d_in[5];
  const float* logb = (const float*)d_in[6];

  char* ws = (char*)d_ws;
  u16*   xb  = (u16*)(ws + 0);            // 4 MB
  u16*   wqb = (u16*)(ws + 4194304);      // 4 MB
  u16*   wkb = (u16*)(ws + 8388608);      // 4 MB
  u16*   wvb = (u16*)(ws + 12582912);     // 2 MB
  u16*   wob = (u16*)(ws + 14680064);     // 2 MB
  float* Yp  = (float*)(ws + 16777216);   // 21 MB partials (qf/kf slots now unused)
  float* Dp  = (float*)(ws + 37748736);   // 320 KB
  u16*   qsb = (u16*)(ws + 50331648);     // 8 MB  [16][2048][128]
  u16*   ksb = (u16*)(ws + 58720256);     // 8 MB
  u16*   vtb = (u16*)(ws + 67108864);     // 4 MB  V^T [16][64][2048]
  u16*   yb  = (u16*)(ws + 71303168);     // 4 MB  [2048][1024]

  conv_all<<<8192, 256, 0, stream>>>(x, Wq, Wk, Wv, Wo, xb, wqb, wkb, wvb, wob);
  qkv_gemm<<<640, 256, 0, stream>>>(xb, wqb, wkb, wvb, qsb, ksb, vtb);
  attn3<<<640, 512, 0, stream>>>(qsb, ksb, vtb, sink, logb, yb, Yp, Dp);
  attn_reduce<<<192, 256, 0, stream>>>(Yp, Dp, sink, logb, yb);
  o_gemm<<<256, 256, 0, stream>>>(yb, wob, (float*)d_out);
}

// Round 10
// 140.698 us; speedup vs baseline: 1.0634x; 1.0632x over previous
//
#include <hip/hip_runtime.h>

typedef __attribute__((ext_vector_type(8))) short bf8v;   // 8 bf16 (4 VGPRs)
typedef __attribute__((ext_vector_type(4))) float f4v;    // MFMA acc
typedef unsigned short u16;
typedef unsigned int   u32;
#define AS1 __attribute__((address_space(1)))
#define AS3 __attribute__((address_space(3)))

__device__ inline u16 f2b(float f){
  u32 u = __builtin_bit_cast(u32, f);
  u += 0x7fffu + ((u >> 16) & 1u);     // RNE
  return (u16)(u >> 16);
}

// ---------------- merged f32 -> bf16 conversion (x, Wq, Wk, Wv, Wo) ----------------
__global__ __launch_bounds__(256) void conv_all(const float* __restrict__ x,  const float* __restrict__ wq,
                                                const float* __restrict__ wk, const float* __restrict__ wv,
                                                const float* __restrict__ wo,
                                                u16* xb, u16* wqb, u16* wkb, u16* wvb, u16* wob){
  int i = blockIdx.x * 256 + threadIdx.x;
  const float* src; u16* dst; int off;
  if      (i <  524288){ src = x;  dst = xb;  off = i; }
  else if (i < 1048576){ src = wq; dst = wqb; off = i -  524288; }
  else if (i < 1572864){ src = wk; dst = wkb; off = i - 1048576; }
  else if (i < 1835008){ src = wv; dst = wvb; off = i - 1572864; }
  else                 { src = wo; dst = wob; off = i - 1835008; }
  float4 v = ((const float4*)src)[off];
  uint2 r;
  r.x = (u32)f2b(v.x) | ((u32)f2b(v.y) << 16);
  r.y = (u32)f2b(v.z) | ((u32)f2b(v.w) << 16);
  ((uint2*)dst)[off] = r;
}

// ---------------- bt-GEMM core (R5 structure): A 128xK tile, B (NFR*32)xK tile, BK=64 ----------
// 2 LDS buffers, prefetch(k+1) BEFORE compute(k), one __syncthreads per step.
// gload_lds w16 linear dest + inverse-swizzled source + swizzled read (k-seg ^ row&7).
template<int NFR>   // 4 -> BN=128, 2 -> BN=64
__device__ __forceinline__ void gemm_core(const u16* __restrict__ A, const u16* __restrict__ B,
                                          int K, int m0, int n0, u16* lds, f4v (&acc)[4][NFR]){
  const int tid = threadIdx.x;
  const int l = tid & 63, w = tid >> 6;
  const int wrow = (w >> 1) * 64, wcol = (w & 1) * (NFR * 16);
  constexpr int SB = 8192 + NFR * 2048;      // buffer stride in elems: A 8192 + B NFR*2048
  #pragma unroll
  for (int a = 0; a < 4; a++)
    #pragma unroll
    for (int b = 0; b < NFR; b++) acc[a][b] = (f4v)0.0f;

  const int crow = l >> 3;                   // 0..7
  const int ksrc = ((l & 7) ^ crow) * 8;     // inverse-swizzled k-segment (elems)

  auto stage = [&](int k0, int buf){
    const u16* Ab = A + (size_t)m0 * K + k0;
    const u16* Bb = B + (size_t)n0 * K + k0;
    u16* At = lds + buf * SB;
    u16* Bt = At + 8192;
    #pragma unroll
    for (int c = 0; c < 4; c++){
      int chunk = w * 4 + c;
      int row = chunk * 8 + crow;
      __builtin_amdgcn_global_load_lds((const AS1 void*)(Ab + (size_t)row * K + ksrc),
                                       (AS3 void*)(At + chunk * 512), 16, 0, 0);
    }
    if constexpr (NFR == 4){
      #pragma unroll
      for (int c = 0; c < 4; c++){
        int chunk = w * 4 + c;
        int row = chunk * 8 + crow;
        __builtin_amdgcn_global_load_lds((const AS1 void*)(Bb + (size_t)row * K + ksrc),
                                         (AS3 void*)(Bt + chunk * 512), 16, 0, 0);
      }
    } else {
      #pragma unroll
      for (int c = 0; c < 2; c++){
        int chunk = w * 2 + c;
        int row = chunk * 8 + crow;
        __builtin_amdgcn_global_load_lds((const AS1 void*)(Bb + (size_t)row * K + ksrc),
                                         (AS3 void*)(Bt + chunk * 512), 16, 0, 0);
      }
    }
  };

  stage(0, 0);
  __syncthreads();
  int buf = 0;
  for (int k0 = 0; k0 < K; k0 += 64){
    if (k0 + 64 < K) stage(k0 + 64, buf ^ 1);   // prefetch overlaps this step's compute
    const u16* At = lds + buf * SB;
    const u16* Bt = At + 8192;
    #pragma unroll
    for (int kk = 0; kk < 2; kk++){
      bf8v af[4], bfr[NFR];
      #pragma unroll
      for (int mr = 0; mr < 4; mr++){
        int row = wrow + mr * 16 + (l & 15);
        af[mr] = *(const bf8v*)(At + row * 64 + (((kk * 32 + (l >> 4) * 8)) ^ ((row & 7) * 8)));
      }
      #pragma unroll
      for (int nc = 0; nc < NFR; nc++){
        int row = wcol + nc * 16 + (l & 15);
        bfr[nc] = *(const bf8v*)(Bt + row * 64 + (((kk * 32 + (l >> 4) * 8)) ^ ((row & 7) * 8)));
      }
      #pragma unroll
      for (int mr = 0; mr < 4; mr++)
        #pragma unroll
        for (int nc = 0; nc < NFR; nc++)
          acc[mr][nc] = __builtin_amdgcn_mfma_f32_16x16x32_bf16(af[mr], bfr[nc], acc[mr][nc], 0, 0, 0);
    }
    __syncthreads();   // drains prefetch + read/write hazard
    buf ^= 1;
  }
}

// Q/K -> bf16 scores qf/kf; V -> transposed bf16 vtb[h][d][t]
__global__ __launch_bounds__(256) void qkv_gemm(const u16* __restrict__ xb,
                                                const u16* __restrict__ wqb, const u16* __restrict__ wkb,
                                                const u16* __restrict__ wvb,
                                                u16* qf, u16* kf, u16* vtb){
  __shared__ u16 lds[32768];   // 64 KB: 2 x (A 16KB + B 16KB)
  int b = (blockIdx.x & 7) * 80 + (blockIdx.x >> 3);   // bijective XCD swizzle (640 = 8*80)
  const u16* Bp; int which;    // 0=Q 1=K 2=V
  if (b < 256)      { Bp = wqb; which = 0; }
  else if (b < 512) { Bp = wkb; which = 1; b -= 256; }
  else              { Bp = wvb; which = 2; b -= 512; }
  int sh = (which == 2) ? 3 : 4;
  int m0 = (b >> sh) * 128, n0 = (b & ((1 << sh) - 1)) * 128;

  f4v acc[4][4];
  gemm_core<4>(xb, Bp, 1024, m0, n0, lds, acc);

  const int l = threadIdx.x & 63, w = threadIdx.x >> 6;
  const int wrow = (w >> 1) * 64, wcol = (w & 1) * 64;
  if (which < 2){
    u16* C = which ? kf : qf;
    #pragma unroll
    for (int mr = 0; mr < 4; mr++)
      #pragma unroll
      for (int nc = 0; nc < 4; nc++)
        #pragma unroll
        for (int rr = 0; rr < 4; rr++){
          int row = m0 + wrow + mr * 16 + (l >> 4) * 4 + rr;
          int col = n0 + wcol + nc * 16 + (l & 15);
          C[(size_t)row * 2048 + col] = f2b(acc[mr][nc][rr]);
        }
  } else {
    // transposed store: vtb[h][d][t], 4 consecutive t packed per uint2
    #pragma unroll
    for (int mr = 0; mr < 4; mr++)
      #pragma unroll
      for (int nc = 0; nc < 4; nc++){
        int gcol = n0 + wcol + nc * 16 + (l & 15);
        int t0 = m0 + wrow + mr * 16 + (l >> 4) * 4;
        uint2 pk;
        pk.x = (u32)f2b(acc[mr][nc][0]) | ((u32)f2b(acc[mr][nc][1]) << 16);
        pk.y = (u32)f2b(acc[mr][nc][2]) | ((u32)f2b(acc[mr][nc][3]) << 16);
        *(uint2*)(vtb + (size_t)gcol * 2048 + t0) = pk;   // gcol = h*64+d
      }
  }
}

// out[2048,1024] = yb @ wob^T — 128x64 tiles -> 256 blocks (1/CU)
__global__ __launch_bounds__(256) void o_gemm(const u16* __restrict__ yb, const u16* __restrict__ wob,
                                              float* out){
  __shared__ u16 lds[24576];   // 48 KB: 2 x (A 16KB + B 8KB)
  int b = (blockIdx.x & 7) * 32 + (blockIdx.x >> 3);   // 256 = 8*32
  int m0 = (b >> 4) * 128, n0 = (b & 15) * 64;
  f4v acc[4][2];
  gemm_core<2>(yb, wob, 1024, m0, n0, lds, acc);
  const int l = threadIdx.x & 63, w = threadIdx.x >> 6;
  const int wrow = (w >> 1) * 64, wcol = (w & 1) * 32;
  #pragma unroll
  for (int mr = 0; mr < 4; mr++)
    #pragma unroll
    for (int nc = 0; nc < 2; nc++)
      #pragma unroll
      for (int rr = 0; rr < 4; rr++){
        int row = m0 + wrow + mr * 16 + (l >> 4) * 4 + rr;
        int col = n0 + wcol + nc * 16 + (l & 15);
        out[(size_t)row * 1024 + col] = acc[mr][nc][rr];
      }
}

// ---------------- ReLU + top-32-of-128: 4 rows per wave, interleaved radix chains (ILP=4) ------
__global__ __launch_bounds__(256) void topk2(const u16* __restrict__ qf, const u16* __restrict__ kf,
                                             u16* __restrict__ qsb, u16* __restrict__ ksb){
  int w = threadIdx.x >> 6, l = threadIdx.x & 63;
  int b = blockIdx.x;
  const u16* src; u16* dst;
  if (b < 2048){ src = qf; dst = qsb; } else { src = kf; dst = ksb; b -= 2048; }
  int base = b * 16 + w * 4;          // 4 rows per wave (row = t*16 + h)
  u32 u0[4], u1[4], pre[4];
  int tt[4], hh[4];
  #pragma unroll
  for (int j = 0; j < 4; j++){
    int r = base + j;
    tt[j] = r >> 4; hh[j] = r & 15;
    u32 pair = ((const u32*)(src + (size_t)tt[j] * 2048 + hh[j] * 128))[l];
    u0[j] = pair & 0xFFFFu; u1[j] = pair >> 16;
    if (u0[j] & 0x8000u) u0[j] = 0;   // ReLU
    if (u1[j] & 0x8000u) u1[j] = 0;
    pre[j] = 0;
  }
  for (int bb = 14; bb >= 0; --bb){
    #pragma unroll
    for (int j = 0; j < 4; j++){      // 4 independent ballot chains in flight
      u32 cand = pre[j] | (1u << bb);
      int c = __builtin_popcountll(__ballot(u0[j] >= cand)) + __builtin_popcountll(__ballot(u1[j] >= cand));
      if (c >= 32) pre[j] = cand;
    }
  }
  #pragma unroll
  for (int j = 0; j < 4; j++){
    u32 o0 = (u0[j] >= pre[j]) ? u0[j] : 0u;
    u32 o1 = (u1[j] >= pre[j]) ? u1[j] : 0u;
    ((u32*)(dst + ((size_t)hh[j] * 2048 + tt[j]) * 128))[l] = o0 | (o1 << 16);
  }
}

// ---------------- chunk-parallel causal p=1 attention (8 waves, dbuf, gload_lds) ----------------
__global__ __launch_bounds__(512) void attn3(const u16* __restrict__ qs, const u16* __restrict__ ks,
                                             const u16* __restrict__ vt, const float* __restrict__ sink,
                                             const float* __restrict__ logbeta, u16* __restrict__ yout,
                                             float* __restrict__ Yp, float* __restrict__ Dp){
  __shared__ u16 Kt[2][8192];
  __shared__ u16 Vt[2][4096];
  __shared__ u16 St[8][16 * 72];
  const int tid = threadIdx.x, l = tid & 63, w = tid >> 6;
  const int b = blockIdx.x;
  const int slot = b >> 3;
  const int h = (b & 7) + 8 * (slot / 40);
  const int u = slot % 40;
  int it, chunk, nch;
  if (u < 4)       { it = u; chunk = 0; nch = 1; }
  else if (u < 12) { it = 4 + ((u - 4) >> 1);  chunk = (u - 4) & 1;  nch = 2; }
  else if (u < 24) { it = 8 + (u - 12) / 3;    chunk = (u - 12) % 3; nch = 3; }
  else             { it = 12 + ((u - 24) >> 2); chunk = (u - 24) & 3; nch = 4; }
  const int tiles = 2 * it + 2;
  const int jt0 = (tiles * chunk) / nch;        // balanced partition
  const int jt1 = (tiles * (chunk + 1)) / nch;
  const int qrow0 = it * 128 + w * 16;
  const float beta = expf(logbeta[0]);

  bf8v qfr[4];
  {
    int trow = qrow0 + (l & 15);
    const u16* qrow = qs + ((size_t)h * 2048 + trow) * 128 + (l >> 4) * 8;
    #pragma unroll
    for (int kk = 0; kk < 4; kk++) qfr[kk] = *(const bf8v*)(qrow + kk * 32);
  }

  f4v accY[4];
  #pragma unroll
  for (int c = 0; c < 4; c++) accY[c] = (f4v)0.0f;
  float dsum[4] = {0.f, 0.f, 0.f, 0.f};

  const u16* kroot = ks + (size_t)h * 2048 * 128;
  const u16* vroot = vt + (size_t)h * 64 * 2048;

  auto stage = [&](int jt, int buf){
    const u16* kbase = kroot + (size_t)jt * 64 * 128;
    #pragma unroll
    for (int i = 0; i < 2; i++){
      int g = i * 512 + tid;
      int r = g >> 4, c = g & 15;
      __builtin_amdgcn_global_load_lds((const AS1 void*)(kbase + r * 128 + (c ^ (r & 7)) * 8),
                                       (AS3 void*)(&Kt[buf][(i * 512 + w * 64) * 8]), 16, 0, 0);
    }
    {
      int d = tid >> 3, c = tid & 7;
      __builtin_amdgcn_global_load_lds((const AS1 void*)(vroot + (size_t)d * 2048 + jt * 64 + (c ^ (d & 7)) * 8),
                                       (AS3 void*)(&Vt[buf][w * 512]), 16, 0, 0);
    }
  };

  stage(jt0, 0);
  __syncthreads();
  int buf = 0;
  for (int jt = jt0; jt < jt1; ++jt){
    if (jt + 1 < jt1) stage(jt + 1, buf ^ 1);

    if (jt * 64 <= qrow0 + 15){
      f4v accS[4];
      #pragma unroll
      for (int c = 0; c < 4; c++) accS[c] = (f4v)0.0f;
      __builtin_amdgcn_s_setprio(1);
      #pragma unroll
      for (int c = 0; c < 4; c++){
        int r = c * 16 + (l & 15);
        #pragma unroll
        for (int kk = 0; kk < 4; kk++){
          int ch = kk * 4 + (l >> 4);
          bf8v kfr = *(const bf8v*)(&Kt[buf][r * 128 + ((ch ^ (r & 7)) * 8)]);
          accS[c] = __builtin_amdgcn_mfma_f32_16x16x32_bf16(qfr[kk], kfr, accS[c], 0, 0, 0);
        }
      }
      __builtin_amdgcn_s_setprio(0);
      if (jt * 64 + 63 > qrow0){
        #pragma unroll
        for (int c = 0; c < 4; c++)
          #pragma unroll
          for (int rr = 0; rr < 4; rr++){
            int i = qrow0 + (l >> 4) * 4 + rr;
            int j = jt * 64 + c * 16 + (l & 15);
            if (j > i) accS[c][rr] = 0.f;
          }
      }
      #pragma unroll
      for (int c = 0; c < 4; c++)
        #pragma unroll
        for (int rr = 0; rr < 4; rr++){
          dsum[rr] += accS[c][rr];
          St[w][((l >> 4) * 4 + rr) * 72 + c * 16 + (l & 15)] = f2b(accS[c][rr]);
        }
      __builtin_amdgcn_s_setprio(1);
      #pragma unroll
      for (int k2 = 0; k2 < 2; k2++){
        bf8v afr = *(const bf8v*)(&St[w][(l & 15) * 72 + k2 * 32 + (l >> 4) * 8]);
        #pragma unroll
        for (int c = 0; c < 4; c++){
          int d = c * 16 + (l & 15);
          int ch = k2 * 4 + (l >> 4);
          bf8v vfr = *(const bf8v*)(&Vt[buf][d * 64 + ((ch ^ (d & 7)) * 8)]);
          accY[c] = __builtin_amdgcn_mfma_f32_16x16x32_bf16(afr, vfr, accY[c], 0, 0, 0);
        }
      }
      __builtin_amdgcn_s_setprio(0);
    }
    __syncthreads();
    buf ^= 1;
  }

  #pragma unroll
  for (int rr = 0; rr < 4; rr++){
    float s = dsum[rr];
    s += __shfl_xor(s, 1, 64);
    s += __shfl_xor(s, 2, 64);
    s += __shfl_xor(s, 4, 64);
    s += __shfl_xor(s, 8, 64);
    dsum[rr] = s;
  }

  if (nch == 1){
    #pragma unroll
    for (int c = 0; c < 4; c++){
      float sv = sink[h * 64 + c * 16 + (l & 15)];
      #pragma unroll
      for (int rr = 0; rr < 4; rr++){
        float den = dsum[rr] + beta;
        float inv = 1.0f / fmaxf(den, 1e-12f);
        float y = (accY[c][rr] + beta * sv) * inv;
        int row = qrow0 + (l >> 4) * 4 + rr;
        yout[(size_t)row * 1024 + h * 64 + c * 16 + (l & 15)] = f2b(y);
      }
    }
  } else {
    float* yp = Yp + ((size_t)h * 40 + u) * 8192;
    #pragma unroll
    for (int c = 0; c < 4; c++)
      #pragma unroll
      for (int rr = 0; rr < 4; rr++){
        int rowib = w * 16 + (l >> 4) * 4 + rr;
        yp[rowib * 64 + c * 16 + (l & 15)] = accY[c][rr];
      }
    if ((l & 15) == 0){
      #pragma unroll
      for (int rr = 0; rr < 4; rr++)
        Dp[((size_t)h * 40 + u) * 128 + w * 16 + (l >> 4) * 4 + rr] = dsum[rr];
    }
  }
}

// combine partials for it 4..15 (grid 16 x 12)
__global__ __launch_bounds__(256) void attn_reduce(const float* __restrict__ Yp, const float* __restrict__ Dp,
                                                   const float* __restrict__ sink, const float* __restrict__ logbeta,
                                                   u16* __restrict__ yout){
  int blk = blockIdx.x;
  int h = blk / 12, it = 4 + blk % 12;
  int nch = it / 4 + 1;
  int u0 = (it < 8) ? 4 + (it - 4) * 2 : (it < 12) ? 12 + (it - 8) * 3 : 24 + (it - 12) * 4;
  float beta = expf(logbeta[0]);
  __shared__ float inv_s[128];
  int t = threadIdx.x;
  if (t < 128){
    float s = 0.f;
    for (int c = 0; c < nch; c++) s += Dp[((size_t)h * 40 + u0 + c) * 128 + t];
    inv_s[t] = 1.0f / fmaxf(s + beta, 1e-12f);
  }
  __syncthreads();
  const float* base = Yp + ((size_t)h * 40 + u0) * 8192;
  #pragma unroll
  for (int e = 0; e < 32; e++){
    int idx = e * 256 + t;
    float acc = 0.f;
    for (int c = 0; c < nch; c++) acc += base[c * 8192 + idx];
    int row = idx >> 6, col = idx & 63;
    float y = (acc + beta * sink[h * 64 + col]) * inv_s[row];
    yout[(size_t)(it * 128 + row) * 1024 + h * 64 + col] = f2b(y);
  }
}

extern "C" void kernel_launch(void* const* d_in, const int* in_sizes, int n_in,
                              void* d_out, int out_size, void* d_ws, size_t ws_size,
                              hipStream_t stream){
  const float* x    = (const float*)d_in[0];
  const float* Wq   = (const float*)d_in[1];
  const float* Wk   = (const float*)d_in[2];
  const float* Wv   = (const float*)d_in[3];
  const float* Wo   = (const float*)d_in[4];
  const float* sink = (const float*)d_in[5];
  const float* logb = (const float*)d_in[6];

  char* ws = (char*)d_ws;
  u16*   xb  = (u16*)(ws + 0);            // 4 MB
  u16*   wqb = (u16*)(ws + 4194304);      // 4 MB
  u16*   wkb = (u16*)(ws + 8388608);      // 4 MB
  u16*   wvb = (u16*)(ws + 12582912);     // 2 MB
  u16*   wob = (u16*)(ws + 14680064);     // 2 MB
  u16*   qf  = (u16*)(ws + 16777216);     // 8 MB bf16 scores (live: qkv_gemm -> topk2)
  u16*   kf  = (u16*)(ws + 33554432);     // 8 MB bf16 scores (live: qkv_gemm -> topk2)
  u16*   qsb = (u16*)(ws + 50331648);     // 8 MB  [16][2048][128]
  u16*   ksb = (u16*)(ws + 58720256);     // 8 MB
  u16*   vtb = (u16*)(ws + 67108864);     // 4 MB  V^T [16][64][2048]
  u16*   yb  = (u16*)(ws + 71303168);     // 4 MB  [2048][1024]
  float* Yp  = (float*)(ws + 16777216);   // 21 MB partials (overlays qf/kf AFTER topk2)
  float* Dp  = (float*)(ws + 37748736);   // 320 KB (dead kf region, after topk2)

  conv_all<<<8192, 256, 0, stream>>>(x, Wq, Wk, Wv, Wo, xb, wqb, wkb, wvb, wob);
  qkv_gemm<<<640, 256, 0, stream>>>(xb, wqb, wkb, wvb, qf, kf, vtb);
  topk2<<<4096, 256, 0, stream>>>(qf, kf, qsb, ksb);
  attn3<<<640, 512, 0, stream>>>(qsb, ksb, vtb, sink, logb, yb, Yp, Dp);
  attn_reduce<<<192, 256, 0, stream>>>(Yp, Dp, sink, logb, yb);
  o_gemm<<<256, 256, 0, stream>>>(yb, wob, (float*)d_out);
}

// Round 11
// 136.745 us; speedup vs baseline: 1.0941x; 1.0289x over previous
//
#include <hip/hip_runtime.h>

typedef __attribute__((ext_vector_type(8))) short bf8v;   // 8 bf16 (4 VGPRs)
typedef __attribute__((ext_vector_type(4))) float f4v;    // MFMA acc
typedef unsigned short u16;
typedef unsigned int   u32;
#define AS1 __attribute__((address_space(1)))
#define AS3 __attribute__((address_space(3)))

__device__ inline u16 f2b(float f){
  u32 u = __builtin_bit_cast(u32, f);
  u += 0x7fffu + ((u >> 16) & 1u);     // RNE
  return (u16)(u >> 16);
}

// ---------------- merged f32 -> bf16 conversion (x, Wq, Wk, Wv, Wo) ----------------
__global__ __launch_bounds__(256) void conv_all(const float* __restrict__ x,  const float* __restrict__ wq,
                                                const float* __restrict__ wk, const float* __restrict__ wv,
                                                const float* __restrict__ wo,
                                                u16* xb, u16* wqb, u16* wkb, u16* wvb, u16* wob){
  int i = blockIdx.x * 256 + threadIdx.x;
  const float* src; u16* dst; int off;
  if      (i <  524288){ src = x;  dst = xb;  off = i; }
  else if (i < 1048576){ src = wq; dst = wqb; off = i -  524288; }
  else if (i < 1572864){ src = wk; dst = wkb; off = i - 1048576; }
  else if (i < 1835008){ src = wv; dst = wvb; off = i - 1572864; }
  else                 { src = wo; dst = wob; off = i - 1835008; }
  float4 v = ((const float4*)src)[off];
  uint2 r;
  r.x = (u32)f2b(v.x) | ((u32)f2b(v.y) << 16);
  r.y = (u32)f2b(v.z) | ((u32)f2b(v.w) << 16);
  ((uint2*)dst)[off] = r;
}

// ---------------- bt-GEMM core: BK=32, 2 buffers (32/24 KB LDS -> 4-5 blocks/CU) ----------------
// prefetch(k+1) BEFORE compute(k), one __syncthreads per step.
// gload_lds w16 linear dest + inverse-swizzled source + swizzled read (k-seg ^ (row>>1)&3).
template<int NFR>   // 4 -> BN=128, 2 -> BN=64
__device__ __forceinline__ void gemm_core(const u16* __restrict__ A, const u16* __restrict__ B,
                                          int K, int m0, int n0, u16* lds, f4v (&acc)[4][NFR]){
  const int tid = threadIdx.x;
  const int l = tid & 63, w = tid >> 6;
  const int wrow = (w >> 1) * 64, wcol = (w & 1) * (NFR * 16);
  constexpr int SB = 4096 + NFR * 1024;      // A 128x32 + B (NFR*32)x32 per buffer
  #pragma unroll
  for (int a = 0; a < 4; a++)
    #pragma unroll
    for (int b = 0; b < NFR; b++) acc[a][b] = (f4v)0.0f;

  const int lrow = l >> 2;                   // 0..15 within a 16-row call
  const int lseg = l & 3;                    // k-segment 0..3

  auto stage = [&](int k0, int buf){
    u16* At = lds + buf * SB;
    u16* Bt = At + 4096;
    #pragma unroll
    for (int j = 0; j < 2; j++){
      int ca = w * 2 + j;
      int row = ca * 16 + lrow;
      int sseg = (lseg ^ ((row >> 1) & 3)) * 8;
      __builtin_amdgcn_global_load_lds((const AS1 void*)(A + (size_t)(m0 + row) * K + k0 + sseg),
                                       (AS3 void*)(At + ca * 512), 16, 0, 0);
    }
    #pragma unroll
    for (int j = 0; j < NFR / 2; j++){
      int cb = w * (NFR / 2) + j;
      int row = cb * 16 + lrow;
      int sseg = (lseg ^ ((row >> 1) & 3)) * 8;
      __builtin_amdgcn_global_load_lds((const AS1 void*)(B + (size_t)(n0 + row) * K + k0 + sseg),
                                       (AS3 void*)(Bt + cb * 512), 16, 0, 0);
    }
  };

  stage(0, 0);
  __syncthreads();
  int buf = 0;
  for (int k0 = 0; k0 < K; k0 += 32){
    if (k0 + 32 < K) stage(k0 + 32, buf ^ 1);   // prefetch overlaps this step's compute
    const u16* At = lds + buf * SB;
    const u16* Bt = At + 4096;
    bf8v af[4], bfr[NFR];
    #pragma unroll
    for (int mr = 0; mr < 4; mr++){
      int row = wrow + mr * 16 + (l & 15);
      af[mr] = *(const bf8v*)(At + row * 32 + (((l >> 4) ^ ((row >> 1) & 3)) * 8));
    }
    #pragma unroll
    for (int nc = 0; nc < NFR; nc++){
      int row = wcol + nc * 16 + (l & 15);
      bfr[nc] = *(const bf8v*)(Bt + row * 32 + (((l >> 4) ^ ((row >> 1) & 3)) * 8));
    }
    #pragma unroll
    for (int mr = 0; mr < 4; mr++)
      #pragma unroll
      for (int nc = 0; nc < NFR; nc++)
        acc[mr][nc] = __builtin_amdgcn_mfma_f32_16x16x32_bf16(af[mr], bfr[nc], acc[mr][nc], 0, 0, 0);
    __syncthreads();   // drains prefetch + read/write hazard
    buf ^= 1;
  }
}

// Q/K -> bf16 scores qf/kf; V -> transposed bf16 vtb[h][d][t]
__global__ __launch_bounds__(256, 4) void qkv_gemm(const u16* __restrict__ xb,
                                                   const u16* __restrict__ wqb, const u16* __restrict__ wkb,
                                                   const u16* __restrict__ wvb,
                                                   u16* qf, u16* kf, u16* vtb){
  __shared__ u16 lds[16384];   // 32 KB: 2 x 8192
  int b = (blockIdx.x & 7) * 80 + (blockIdx.x >> 3);   // bijective XCD swizzle (640 = 8*80)
  const u16* Bp; int which;    // 0=Q 1=K 2=V
  if (b < 256)      { Bp = wqb; which = 0; }
  else if (b < 512) { Bp = wkb; which = 1; b -= 256; }
  else              { Bp = wvb; which = 2; b -= 512; }
  int sh = (which == 2) ? 3 : 4;
  int m0 = (b >> sh) * 128, n0 = (b & ((1 << sh) - 1)) * 128;

  f4v acc[4][4];
  gemm_core<4>(xb, Bp, 1024, m0, n0, lds, acc);

  const int l = threadIdx.x & 63, w = threadIdx.x >> 6;
  const int wrow = (w >> 1) * 64, wcol = (w & 1) * 64;
  if (which < 2){
    u16* C = which ? kf : qf;
    #pragma unroll
    for (int mr = 0; mr < 4; mr++)
      #pragma unroll
      for (int nc = 0; nc < 4; nc++)
        #pragma unroll
        for (int rr = 0; rr < 4; rr++){
          int row = m0 + wrow + mr * 16 + (l >> 4) * 4 + rr;
          int col = n0 + wcol + nc * 16 + (l & 15);
          C[(size_t)row * 2048 + col] = f2b(acc[mr][nc][rr]);
        }
  } else {
    // transposed store: vtb[h][d][t], 4 consecutive t packed per uint2
    #pragma unroll
    for (int mr = 0; mr < 4; mr++)
      #pragma unroll
      for (int nc = 0; nc < 4; nc++){
        int gcol = n0 + wcol + nc * 16 + (l & 15);
        int t0 = m0 + wrow + mr * 16 + (l >> 4) * 4;
        uint2 pk;
        pk.x = (u32)f2b(acc[mr][nc][0]) | ((u32)f2b(acc[mr][nc][1]) << 16);
        pk.y = (u32)f2b(acc[mr][nc][2]) | ((u32)f2b(acc[mr][nc][3]) << 16);
        *(uint2*)(vtb + (size_t)gcol * 2048 + t0) = pk;   // gcol = h*64+d
      }
  }
}

// out[2048,1024] = yb @ wob^T — 128x64 tiles -> 256 blocks
__global__ __launch_bounds__(256, 4) void o_gemm(const u16* __restrict__ yb, const u16* __restrict__ wob,
                                                 float* out){
  __shared__ u16 lds[12288];   // 24 KB: 2 x 6144
  int b = (blockIdx.x & 7) * 32 + (blockIdx.x >> 3);   // 256 = 8*32
  int m0 = (b >> 4) * 128, n0 = (b & 15) * 64;
  f4v acc[4][2];
  gemm_core<2>(yb, wob, 1024, m0, n0, lds, acc);
  const int l = threadIdx.x & 63, w = threadIdx.x >> 6;
  const int wrow = (w >> 1) * 64, wcol = (w & 1) * 32;
  #pragma unroll
  for (int mr = 0; mr < 4; mr++)
    #pragma unroll
    for (int nc = 0; nc < 2; nc++)
      #pragma unroll
      for (int rr = 0; rr < 4; rr++){
        int row = m0 + wrow + mr * 16 + (l >> 4) * 4 + rr;
        int col = n0 + wcol + nc * 16 + (l & 15);
        out[(size_t)row * 1024 + col] = acc[mr][nc][rr];
      }
}

// ---------------- ReLU + top-32-of-128: 4 rows per wave, interleaved radix chains (ILP=4) ------
__global__ __launch_bounds__(256) void topk2(const u16* __restrict__ qf, const u16* __restrict__ kf,
                                             u16* __restrict__ qsb, u16* __restrict__ ksb){
  int w = threadIdx.x >> 6, l = threadIdx.x & 63;
  int b = blockIdx.x;
  const u16* src; u16* dst;
  if (b < 2048){ src = qf; dst = qsb; } else { src = kf; dst = ksb; b -= 2048; }
  int base = b * 16 + w * 4;          // 4 rows per wave (row = t*16 + h)
  u32 u0[4], u1[4], pre[4];
  int tt[4], hh[4];
  #pragma unroll
  for (int j = 0; j < 4; j++){
    int r = base + j;
    tt[j] = r >> 4; hh[j] = r & 15;
    u32 pair = ((const u32*)(src + (size_t)tt[j] * 2048 + hh[j] * 128))[l];
    u0[j] = pair & 0xFFFFu; u1[j] = pair >> 16;
    if (u0[j] & 0x8000u) u0[j] = 0;   // ReLU
    if (u1[j] & 0x8000u) u1[j] = 0;
    pre[j] = 0;
  }
  for (int bb = 14; bb >= 0; --bb){
    #pragma unroll
    for (int j = 0; j < 4; j++){      // 4 independent ballot chains in flight
      u32 cand = pre[j] | (1u << bb);
      int c = __builtin_popcountll(__ballot(u0[j] >= cand)) + __builtin_popcountll(__ballot(u1[j] >= cand));
      if (c >= 32) pre[j] = cand;
    }
  }
  #pragma unroll
  for (int j = 0; j < 4; j++){
    u32 o0 = (u0[j] >= pre[j]) ? u0[j] : 0u;
    u32 o1 = (u1[j] >= pre[j]) ? u1[j] : 0u;
    ((u32*)(dst + ((size_t)hh[j] * 2048 + tt[j]) * 128))[l] = o0 | (o1 << 16);
  }
}

// ---------------- chunk-parallel causal p=1 attention ----------------
// K single-buffered (16 KB) + V double-buffered: 50 KB LDS -> 3 blocks/CU.
__global__ __launch_bounds__(512, 6) void attn3(const u16* __restrict__ qs, const u16* __restrict__ ks,
                                                const u16* __restrict__ vt, const float* __restrict__ sink,
                                                const float* __restrict__ logbeta, u16* __restrict__ yout,
                                                float* __restrict__ Yp, float* __restrict__ Dp){
  __shared__ u16 Kt[8192];        // [64 rows][128] chunk-swizzled, single buffer
  __shared__ u16 Vt[2][4096];     // [buf][64 d][64 j] chunk-swizzled
  __shared__ u16 St[8][16 * 72];  // per-wave S slabs
  const int tid = threadIdx.x, l = tid & 63, w = tid >> 6;
  const int b = blockIdx.x;
  const int slot = b >> 3;
  const int h = (b & 7) + 8 * (slot / 40);
  const int u = slot % 40;
  int it, chunk, nch;
  if (u < 4)       { it = u; chunk = 0; nch = 1; }
  else if (u < 12) { it = 4 + ((u - 4) >> 1);  chunk = (u - 4) & 1;  nch = 2; }
  else if (u < 24) { it = 8 + (u - 12) / 3;    chunk = (u - 12) % 3; nch = 3; }
  else             { it = 12 + ((u - 24) >> 2); chunk = (u - 24) & 3; nch = 4; }
  const int tiles = 2 * it + 2;
  const int jt0 = (tiles * chunk) / nch;        // balanced partition
  const int jt1 = (tiles * (chunk + 1)) / nch;
  const int qrow0 = it * 128 + w * 16;
  const float beta = expf(logbeta[0]);

  bf8v qfr[4];
  {
    int trow = qrow0 + (l & 15);
    const u16* qrow = qs + ((size_t)h * 2048 + trow) * 128 + (l >> 4) * 8;
    #pragma unroll
    for (int kk = 0; kk < 4; kk++) qfr[kk] = *(const bf8v*)(qrow + kk * 32);
  }

  f4v accY[4];
  #pragma unroll
  for (int c = 0; c < 4; c++) accY[c] = (f4v)0.0f;
  float dsum[4] = {0.f, 0.f, 0.f, 0.f};

  const u16* kroot = ks + (size_t)h * 2048 * 128;
  const u16* vroot = vt + (size_t)h * 64 * 2048;

  auto stageK = [&](int jt){
    const u16* kbase = kroot + (size_t)jt * 64 * 128;
    #pragma unroll
    for (int i = 0; i < 2; i++){
      int g = i * 512 + tid;
      int r = g >> 4, c = g & 15;
      __builtin_amdgcn_global_load_lds((const AS1 void*)(kbase + r * 128 + (c ^ (r & 7)) * 8),
                                       (AS3 void*)(&Kt[(i * 512 + w * 64) * 8]), 16, 0, 0);
    }
  };
  auto stageV = [&](int jt, int b2){
    int d = tid >> 3, c = tid & 7;
    __builtin_amdgcn_global_load_lds((const AS1 void*)(vroot + (size_t)d * 2048 + jt * 64 + (c ^ (d & 7)) * 8),
                                     (AS3 void*)(&Vt[b2][w * 512]), 16, 0, 0);
  };

  stageK(jt0);
  stageV(jt0, 0);
  __syncthreads();
  int buf = 0;
  for (int jt = jt0; jt < jt1; ++jt){
    bool pf = (jt + 1 < jt1);
    if (pf) stageV(jt + 1, buf ^ 1);
    const bool act = (jt * 64 <= qrow0 + 15);

    f4v accS[4];
    if (act){
      #pragma unroll
      for (int c = 0; c < 4; c++) accS[c] = (f4v)0.0f;
      __builtin_amdgcn_s_setprio(1);
      #pragma unroll
      for (int c = 0; c < 4; c++){
        int r = c * 16 + (l & 15);
        #pragma unroll
        for (int kk = 0; kk < 4; kk++){
          int ch = kk * 4 + (l >> 4);
          bf8v kfr = *(const bf8v*)(&Kt[r * 128 + ((ch ^ (r & 7)) * 8)]);
          accS[c] = __builtin_amdgcn_mfma_f32_16x16x32_bf16(qfr[kk], kfr, accS[c], 0, 0, 0);
        }
      }
      __builtin_amdgcn_s_setprio(0);
    }
    // raw barrier: every wave's Kt reads were consumed (lgkm-waited) before arrival;
    // no vmcnt drain here so the V prefetch stays in flight.
    __builtin_amdgcn_s_barrier();
    __builtin_amdgcn_sched_barrier(0);
    if (pf) stageK(jt + 1);            // overwrite Kt; overlaps softmax+PV below

    if (act){
      if (jt * 64 + 63 > qrow0){
        #pragma unroll
        for (int c = 0; c < 4; c++)
          #pragma unroll
          for (int rr = 0; rr < 4; rr++){
            int i = qrow0 + (l >> 4) * 4 + rr;
            int j = jt * 64 + c * 16 + (l & 15);
            if (j > i) accS[c][rr] = 0.f;
          }
      }
      #pragma unroll
      for (int c = 0; c < 4; c++)
        #pragma unroll
        for (int rr = 0; rr < 4; rr++){
          dsum[rr] += accS[c][rr];
          St[w][((l >> 4) * 4 + rr) * 72 + c * 16 + (l & 15)] = f2b(accS[c][rr]);
        }
      __builtin_amdgcn_s_setprio(1);
      #pragma unroll
      for (int k2 = 0; k2 < 2; k2++){
        bf8v afr = *(const bf8v*)(&St[w][(l & 15) * 72 + k2 * 32 + (l >> 4) * 8]);
        #pragma unroll
        for (int c = 0; c < 4; c++){
          int d = c * 16 + (l & 15);
          int ch = k2 * 4 + (l >> 4);
          bf8v vfr = *(const bf8v*)(&Vt[buf][d * 64 + ((ch ^ (d & 7)) * 8)]);
          accY[c] = __builtin_amdgcn_mfma_f32_16x16x32_bf16(afr, vfr, accY[c], 0, 0, 0);
        }
      }
      __builtin_amdgcn_s_setprio(0);
    }
    __syncthreads();   // drains this wave's K(jt+1)+V(jt+1) loads; read/write hazard for Vt[buf]
    buf ^= 1;
  }

  #pragma unroll
  for (int rr = 0; rr < 4; rr++){
    float s = dsum[rr];
    s += __shfl_xor(s, 1, 64);
    s += __shfl_xor(s, 2, 64);
    s += __shfl_xor(s, 4, 64);
    s += __shfl_xor(s, 8, 64);
    dsum[rr] = s;
  }

  if (nch == 1){
    #pragma unroll
    for (int c = 0; c < 4; c++){
      float sv = sink[h * 64 + c * 16 + (l & 15)];
      #pragma unroll
      for (int rr = 0; rr < 4; rr++){
        float den = dsum[rr] + beta;
        float inv = 1.0f / fmaxf(den, 1e-12f);
        float y = (accY[c][rr] + beta * sv) * inv;
        int row = qrow0 + (l >> 4) * 4 + rr;
        yout[(size_t)row * 1024 + h * 64 + c * 16 + (l & 15)] = f2b(y);
      }
    }
  } else {
    float* yp = Yp + ((size_t)h * 40 + u) * 8192;
    #pragma unroll
    for (int c = 0; c < 4; c++)
      #pragma unroll
      for (int rr = 0; rr < 4; rr++){
        int rowib = w * 16 + (l >> 4) * 4 + rr;
        yp[rowib * 64 + c * 16 + (l & 15)] = accY[c][rr];
      }
    if ((l & 15) == 0){
      #pragma unroll
      for (int rr = 0; rr < 4; rr++)
        Dp[((size_t)h * 40 + u) * 128 + w * 16 + (l >> 4) * 4 + rr] = dsum[rr];
    }
  }
}

// combine partials for it 4..15 (grid 16 x 12)
__global__ __launch_bounds__(256) void attn_reduce(const float* __restrict__ Yp, const float* __restrict__ Dp,
                                                   const float* __restrict__ sink, const float* __restrict__ logbeta,
                                                   u16* __restrict__ yout){
  int blk = blockIdx.x;
  int h = blk / 12, it = 4 + blk % 12;
  int nch = it / 4 + 1;
  int u0 = (it < 8) ? 4 + (it - 4) * 2 : (it < 12) ? 12 + (it - 8) * 3 : 24 + (it - 12) * 4;
  float beta = expf(logbeta[0]);
  __shared__ float inv_s[128];
  int t = threadIdx.x;
  if (t < 128){
    float s = 0.f;
    for (int c = 0; c < nch; c++) s += Dp[((size_t)h * 40 + u0 + c) * 128 + t];
    inv_s[t] = 1.0f / fmaxf(s + beta, 1e-12f);
  }
  __syncthreads();
  const float* base = Yp + ((size_t)h * 40 + u0) * 8192;
  #pragma unroll
  for (int e = 0; e < 32; e++){
    int idx = e * 256 + t;
    float acc = 0.f;
    for (int c = 0; c < nch; c++) acc += base[c * 8192 + idx];
    int row = idx >> 6, col = idx & 63;
    float y = (acc + beta * sink[h * 64 + col]) * inv_s[row];
    yout[(size_t)(it * 128 + row) * 1024 + h * 64 + col] = f2b(y);
  }
}

extern "C" void kernel_launch(void* const* d_in, const int* in_sizes, int n_in,
                              void* d_out, int out_size, void* d_ws, size_t ws_size,
                              hipStream_t stream){
  const float* x    = (const float*)d_in[0];
  const float* Wq   = (const float*)d_in[1];
  const float* Wk   = (const float*)d_in[2];
  const float* Wv   = (const float*)d_in[3];
  const float* Wo   = (const float*)d_in[4];
  const float* sink = (const float*)d_in[5];
  const float* logb = (const float*)d_in[6];

  char* ws = (char*)d_ws;
  u16*   xb  = (u16*)(ws + 0);            // 4 MB
  u16*   wqb = (u16*)(ws + 4194304);      // 4 MB
  u16*   wkb = (u16*)(ws + 8388608);      // 4 MB
  u16*   wvb = (u16*)(ws + 12582912);     // 2 MB
  u16*   wob = (u16*)(ws + 14680064);     // 2 MB
  u16*   qf  = (u16*)(ws + 16777216);     // 8 MB bf16 scores (live: qkv_gemm -> topk2)
  u16*   kf  = (u16*)(ws + 33554432);     // 8 MB bf16 scores (live: qkv_gemm -> topk2)
  u16*   qsb = (u16*)(ws + 50331648);     // 8 MB  [16][2048][128]
  u16*   ksb = (u16*)(ws + 58720256);     // 8 MB
  u16*   vtb = (u16*)(ws + 67108864);     // 4 MB  V^T [16][64][2048]
  u16*   yb  = (u16*)(ws + 71303168);     // 4 MB  [2048][1024]
  float* Yp  = (float*)(ws + 16777216);   // 21 MB partials (overlays qf/kf AFTER topk2)
  float* Dp  = (float*)(ws + 37748736);   // 320 KB (dead kf region, after topk2)

  conv_all<<<8192, 256, 0, stream>>>(x, Wq, Wk, Wv, Wo, xb, wqb, wkb, wvb, wob);
  qkv_gemm<<<640, 256, 0, stream>>>(xb, wqb, wkb, wvb, qf, kf, vtb);
  topk2<<<4096, 256, 0, stream>>>(qf, kf, qsb, ksb);
  attn3<<<640, 512, 0, stream>>>(qsb, ksb, vtb, sink, logb, yb, Yp, Dp);
  attn_reduce<<<192, 256, 0, stream>>>(Yp, Dp, sink, logb, yb);
  o_gemm<<<256, 256, 0, stream>>>(yb, wob, (float*)d_out);
}